// Round 11
// baseline (206.382 us; speedup 1.0000x reference)
//
#include <hip/hip_runtime.h>
#include <stdint.h>

#define B_ 4
#define C_ 64
#define H_ 96
#define W_ 96
#define HP_ 48
#define WP_ 48
#define N_ (H_*W_)      // 9216
#define M_ (HP_*WP_)    // 2304
#define KD_ 64
#define OD_ 64
#define BN_EPS 1e-5f
#define LOG2E 1.4426950408889634f
#define SHIFT2 28.853900817779268f   // 20 * LOG2E
#define QT_ 48                        // q-tile: 768 blocks = exactly 3/CU (balanced!)
#define QB_ (N_/QT_)                  // 192 q-tiles per batch

typedef __bf16 bf16_t;
typedef bf16_t bf16x8 __attribute__((ext_vector_type(8)));
typedef bf16_t bf16x4 __attribute__((ext_vector_type(4)));
typedef float f32x4 __attribute__((ext_vector_type(4)));
typedef short short4v __attribute__((ext_vector_type(4)));

static __device__ __forceinline__ unsigned short f2bf(float f) {
    unsigned int u = __builtin_bit_cast(unsigned int, f);
    u += 0x7fffu + ((u >> 16) & 1u);
    return (unsigned short)(u >> 16);
}

// Host-safe wrapper (builtin only exists in the device pass; R4/R6 verified
// this MFMA's C/D layout on HW: absmax 0.03125).
static __device__ __forceinline__ f32x4 mfma16_bf16(short4v a, short4v b, f32x4 c) {
#if __has_builtin(__builtin_amdgcn_mfma_f32_16x16x16bf16_1k)
    return __builtin_amdgcn_mfma_f32_16x16x16bf16_1k(a, b, c, 0, 0, 0);
#else
    return c;  // host pass only — never executed on device
#endif
}

// ---------------- Kernel 1: fused pool(x,c2) + key conv + edge attention ----------------
// ea output pre-scaled by LOG2E.
__global__ __launch_bounds__(256) void prep_kernel(
    const float* __restrict__ x, const float* __restrict__ c2,
    const float* __restrict__ wq, const float* __restrict__ bq,
    const float* __restrict__ w1, const float* __restrict__ bnw, const float* __restrict__ bnb,
    const float* __restrict__ bnm, const float* __restrict__ bnv,
    const float* __restrict__ w2, const float* __restrict__ b2,
    unsigned short* __restrict__ kb, unsigned short* __restrict__ vb, float* __restrict__ ea) {

    __shared__ float lw1[OD_*2*C_];
    __shared__ float lwq[KD_*C_];
    __shared__ float xs[C_*33];
    __shared__ float c2s[C_*33];
    __shared__ float red[8][32];

    int tid = threadIdx.x;
    int b = blockIdx.x / 72;
    int m0 = (blockIdx.x % 72) * 32;

    for (int i = tid; i < OD_*2*C_; i += 256) lw1[i] = w1[i];
    for (int i = tid; i < KD_*C_; i += 256) lwq[i] = wq[i];
    for (int j = tid; j < 2048; j += 256) {
        int c = j >> 5, p = j & 31;
        int m = m0 + p;
        int hp = m / WP_, wp = m % WP_;
        size_t base = ((size_t)(b*C_ + c)*H_ + 2*hp)*W_ + 2*wp;
        const float* px = x + base;
        float mx = fmaxf(fmaxf(px[0], px[1]), fmaxf(px[W_], px[W_+1]));
        xs[c*33 + p] = mx;
        vb[(size_t)(b*C_ + c)*M_ + m] = f2bf(mx);
        const float* pc = c2 + base;
        c2s[c*33 + p] = fmaxf(fmaxf(pc[0], pc[1]), fmaxf(pc[W_], pc[W_+1]));
    }
    __syncthreads();

    int ml = tid & 31, oz = tid >> 5;
    int m = m0 + ml;

    float h[8] = {0,0,0,0,0,0,0,0};
    for (int c = 0; c < C_; c += 4) {
        float x0 = xs[c*33+ml], x1 = xs[(c+1)*33+ml], x2 = xs[(c+2)*33+ml], x3 = xs[(c+3)*33+ml];
        #pragma unroll
        for (int oi = 0; oi < 8; oi++) {
            const float4 wv = *(const float4*)&lwq[(oz*8 + oi)*C_ + c];
            h[oi] = fmaf(wv.x, x0, fmaf(wv.y, x1, fmaf(wv.z, x2, fmaf(wv.w, x3, h[oi]))));
        }
    }
    unsigned short tmp[8];
    #pragma unroll
    for (int oi = 0; oi < 8; oi++) tmp[oi] = f2bf(h[oi] + bq[oz*8 + oi]);
    *(uint4*)&kb[((size_t)b*M_ + m)*KD_ + oz*8] = *(const uint4*)tmp;

    float g[8] = {0,0,0,0,0,0,0,0};
    for (int c = 0; c < 2*C_; c += 4) {
        const float* srcb = (c < C_) ? &c2s[c*33] : &xs[(c - C_)*33];
        float x0 = srcb[ml], x1 = srcb[33+ml], x2 = srcb[66+ml], x3 = srcb[99+ml];
        #pragma unroll
        for (int oi = 0; oi < 8; oi++) {
            const float4 wv = *(const float4*)&lw1[(oz*8 + oi)*(2*C_) + c];
            g[oi] = fmaf(wv.x, x0, fmaf(wv.y, x1, fmaf(wv.z, x2, fmaf(wv.w, x3, g[oi]))));
        }
    }
    float z = 0.f;
    #pragma unroll
    for (int oi = 0; oi < 8; oi++) {
        int o = oz*8 + oi;
        float sc = bnw[o] * rsqrtf(bnv[o] + BN_EPS);
        float t = (g[oi] - bnm[o]) * sc + bnb[o];
        z += w2[o] * fmaxf(t, 0.f);
    }
    red[oz][ml] = z;
    __syncthreads();
    if (oz == 0) {
        float s = b2[0];
        #pragma unroll
        for (int i = 0; i < 8; i++) s += red[i][ml];
        ea[(size_t)b*M_ + m] = LOG2E / (1.f + __builtin_amdgcn_exp2f(-s * LOG2E));
    }
}

// ---------------- Kernel 2: query conv at full res -> bf16 [b][n][64] ----------------
__global__ __launch_bounds__(256) void qk_kernel(const float* __restrict__ in, const float* __restrict__ wq,
    const float* __restrict__ bq, unsigned short* __restrict__ outb) {
    __shared__ float lw[KD_*C_];
    for (int i = threadIdx.x; i < KD_*C_; i += 256) lw[i] = wq[i];
    __syncthreads();
    int ml = threadIdx.x & 31, oz = threadIdx.x >> 5;
    int pg = blockIdx.x * 32 + ml;
    float h[8] = {0,0,0,0,0,0,0,0};
    const float* src = in + ((size_t)(pg / N_))*C_*N_ + (pg % N_);
    for (int c = 0; c < C_; c += 4) {
        float x0 = src[(size_t)c*N_], x1 = src[(size_t)(c+1)*N_];
        float x2 = src[(size_t)(c+2)*N_], x3 = src[(size_t)(c+3)*N_];
        #pragma unroll
        for (int oi = 0; oi < 8; oi++) {
            const float4 wv = *(const float4*)&lw[(oz*8 + oi)*C_ + c];
            h[oi] = fmaf(wv.x, x0, fmaf(wv.y, x1, fmaf(wv.z, x2, fmaf(wv.w, x3, h[oi]))));
        }
    }
    unsigned short tmp[8];
    #pragma unroll
    for (int oi = 0; oi < 8; oi++) tmp[oi] = f2bf(h[oi] + bq[oz*8 + oi]);
    *(uint4*)&outb[(size_t)pg*KD_ + oz*8] = *(const uint4*)tmp;
}

// ---------------- Kernel 3: flash attention, barrier-free main loop ----------------
// grid = 768 (exactly 3 blocks/CU), block = 256 (4 waves) = 48 q-rows of one batch.
// XCD swizzle: batch = (blk&7)>>1 -> each batch's ~1.8 MB K/V/Q set lives in one
// 2-XCD L2 pair (R9: FETCH 17.8->9.3 MB). Wave w reads its m-substrip K/V frags
// DIRECTLY from global (L2-resident) with register depth-1 prefetch — zero
// __syncthreads in the main loop, so waves free-run instead of draining vmcnt
// at a per-tile barrier. P stays in registers (S^T D-layout == K=16 MFMA
// B-layout); denominator via all-ones A-frag MFMA (R10-verified).
__global__ __launch_bounds__(256, 3) void attn_kernel(
    const unsigned short* __restrict__ qb, const unsigned short* __restrict__ kb,
    const unsigned short* __restrict__ vb, const float* __restrict__ ea,
    const float* __restrict__ x, const float* __restrict__ gamma_p, float* __restrict__ out) {

    // epilogue only: o_red 2*48*68*4 = 26112 + l_red 768 -> 26880 B
    __shared__ __align__(16) char smem[26880];

    int tid = threadIdx.x;
    int wave = tid >> 6, lane = tid & 63, quad = lane >> 4, l16 = lane & 15;
    int blk = blockIdx.x;
    int b = (blk & 7) >> 1;                       // batch pinned to XCD pair
    int n_base = ((blk & 1) * (QB_/2) + (blk >> 3)) * QT_;

    // Q B-frags: B[col = q = qi*16+l16][k = quad*8+j]
    bf16x8 qf[3][2];
    #pragma unroll
    for (int qi = 0; qi < 3; qi++) {
        const unsigned short* qp = qb + ((size_t)b*N_ + n_base + qi*16 + l16)*KD_;
        qf[qi][0] = __builtin_bit_cast(bf16x8, *(const uint4*)(qp + quad*8));
        qf[qi][1] = __builtin_bit_cast(bf16x8, *(const uint4*)(qp + 32 + quad*8));
    }

    f32x4 o2[3][4];   // O^T partial: [qi][ct]; D: row=c=ct*16+quad*4+r, col=q=qi*16+l16
    f32x4 lacc[3];    // denominator partials via ones-MFMA (all D rows identical)
    #pragma unroll
    for (int qi = 0; qi < 3; qi++) {
        lacc[qi] = (f32x4){0.f,0.f,0.f,0.f};
        #pragma unroll
        for (int ct = 0; ct < 4; ct++) o2[qi][ct] = (f32x4){0.f,0.f,0.f,0.f};
    }
    const short one_bf = (short)0x3F80;  // bf16 1.0
    short4v ones = (short4v){one_bf, one_bf, one_bf, one_bf};

    // per-wave strip base addresses (strip m = mt*64 + wave*16 + ...)
    const unsigned short* kW = kb + ((size_t)b*M_ + wave*16 + l16)*KD_ + quad*8;
    const unsigned short* vW = vb + (size_t)b*C_*M_ + (size_t)(l16)*M_ + wave*16 + quad*4;
    const float* eaW = ea + (size_t)b*M_ + wave*16 + quad*4;

    // register prefetch (depth 1)
    uint4 kf0r = *(const uint4*)(kW);
    uint4 kf1r = *(const uint4*)(kW + 32);
    uint2 var[4];
    #pragma unroll
    for (int ct = 0; ct < 4; ct++)
        var[ct] = *(const uint2*)(vW + (size_t)(ct*16)*M_);
    f32x4 e4r = *(const f32x4*)(eaW);

    for (int mt = 0; mt < M_/64; mt++) {
        bf16x8 kf0 = __builtin_bit_cast(bf16x8, kf0r);
        bf16x8 kf1 = __builtin_bit_cast(bf16x8, kf1r);
        short4v va[4];
        #pragma unroll
        for (int ct = 0; ct < 4; ct++) va[ct] = __builtin_bit_cast(short4v, var[ct]);
        f32x4 e4 = e4r;

        if (mt < M_/64 - 1) {
            int mb = (mt+1) * 64;
            kf0r = *(const uint4*)(kW + (size_t)mb*KD_);
            kf1r = *(const uint4*)(kW + (size_t)mb*KD_ + 32);
            #pragma unroll
            for (int ct = 0; ct < 4; ct++)
                var[ct] = *(const uint2*)(vW + (size_t)(ct*16)*M_ + mb);
            e4r = *(const f32x4*)(eaW + mb);
        }

        // S^T strip: D[m_local = quad*4+r][q = qi*16+l16]
        f32x4 st[3];
        #pragma unroll
        for (int qi = 0; qi < 3; qi++) {
            f32x4 z = (f32x4){0.f,0.f,0.f,0.f};
            z = __builtin_amdgcn_mfma_f32_16x16x32_bf16(kf0, qf[qi][0], z, 0, 0, 0);
            z = __builtin_amdgcn_mfma_f32_16x16x32_bf16(kf1, qf[qi][1], z, 0, 0, 0);
            st[qi] = z;
        }

        // fixed-shift softmax numerators; packed cvt (v_cvt_pk_bf16_f32)
        short4v pk[3];
        #pragma unroll
        for (int qi = 0; qi < 3; qi++) {
            f32x4 p;
            p[0] = __builtin_amdgcn_exp2f(fmaf(st[qi][0], e4[0], -SHIFT2));
            p[1] = __builtin_amdgcn_exp2f(fmaf(st[qi][1], e4[1], -SHIFT2));
            p[2] = __builtin_amdgcn_exp2f(fmaf(st[qi][2], e4[2], -SHIFT2));
            p[3] = __builtin_amdgcn_exp2f(fmaf(st[qi][3], e4[3], -SHIFT2));
            pk[qi] = __builtin_bit_cast(short4v, __builtin_convertvector(p, bf16x4));
        }

        // PV + denominator (ones-A), all register operands
        #pragma unroll
        for (int ct = 0; ct < 4; ct++)
            #pragma unroll
            for (int qi = 0; qi < 3; qi++)
                o2[qi][ct] = mfma16_bf16(va[ct], pk[qi], o2[qi][ct]);
        #pragma unroll
        for (int qi = 0; qi < 3; qi++)
            lacc[qi] = mfma16_bf16(ones, pk[qi], lacc[qi]);
    }

    // ---- epilogue: cross-wave reduction of O^T partials and denominators ----
    float* o_red0 = (float*)smem;            // [48 q][68 c]
    float* o_red1 = o_red0 + 48*68;
    float* l_red  = o_red1 + 48*68;          // [4][48]

    if (lane < 16) {
        #pragma unroll
        for (int qi = 0; qi < 3; qi++) l_red[wave*48 + qi*16 + l16] = lacc[qi][0];
    }
    if (wave < 2) {
        float* od = (wave == 0) ? o_red0 : o_red1;
        #pragma unroll
        for (int qi = 0; qi < 3; qi++)
            #pragma unroll
            for (int ct = 0; ct < 4; ct++)
                *(f32x4*)&od[(qi*16 + l16)*68 + ct*16 + quad*4] = o2[qi][ct];
    }
    __syncthreads();
    if (wave >= 2) {
        float* od = (wave == 2) ? o_red0 : o_red1;
        #pragma unroll
        for (int qi = 0; qi < 3; qi++)
            #pragma unroll
            for (int ct = 0; ct < 4; ct++) {
                f32x4* p = (f32x4*)&od[(qi*16 + l16)*68 + ct*16 + quad*4];
                *p += o2[qi][ct];
            }
    }
    __syncthreads();
    if (tid < 48) {
        float s = (l_red[tid] + l_red[48 + tid]) + (l_red[96 + tid] + l_red[144 + tid]);
        l_red[tid] = 1.f / s;
    }
    __syncthreads();

    float gmm = gamma_p[0];
    int c = tid >> 2, q4 = tid & 3;
    const float* xrow = x + ((size_t)b*C_ + c)*N_ + n_base;
    float* orow = out + ((size_t)b*C_ + c)*N_ + n_base;
    #pragma unroll
    for (int i = 0; i < 3; i++) {
        int q0 = q4*4 + i*16;
        float4 xv = *(const float4*)(xrow + q0);
        float4 ov;
        float v0 = (o_red0[(q0+0)*68 + c] + o_red1[(q0+0)*68 + c]) * l_red[q0+0];
        float v1 = (o_red0[(q0+1)*68 + c] + o_red1[(q0+1)*68 + c]) * l_red[q0+1];
        float v2 = (o_red0[(q0+2)*68 + c] + o_red1[(q0+2)*68 + c]) * l_red[q0+2];
        float v3 = (o_red0[(q0+3)*68 + c] + o_red1[(q0+3)*68 + c]) * l_red[q0+3];
        ov.x = fmaf(gmm, v0, xv.x);
        ov.y = fmaf(gmm, v1, xv.y);
        ov.z = fmaf(gmm, v2, xv.z);
        ov.w = fmaf(gmm, v3, xv.w);
        *(float4*)(orow + q0) = ov;
    }
}

extern "C" void kernel_launch(void* const* d_in, const int* in_sizes, int n_in,
                              void* d_out, int out_size, void* d_ws, size_t ws_size,
                              hipStream_t stream) {
    const float* c2    = (const float*)d_in[0];
    const float* x     = (const float*)d_in[1];
    const float* w_ea1 = (const float*)d_in[2];
    const float* bn_w  = (const float*)d_in[3];
    const float* bn_b  = (const float*)d_in[4];
    const float* bn_m  = (const float*)d_in[5];
    const float* bn_v  = (const float*)d_in[6];
    const float* w_ea2 = (const float*)d_in[7];
    const float* b_ea2 = (const float*)d_in[8];
    const float* w_q   = (const float*)d_in[9];
    const float* b_q   = (const float*)d_in[10];
    const float* gamma = (const float*)d_in[11];
    float* out = (float*)d_out;

    char* ws = (char*)d_ws;
    float* ea            = (float*)(ws + 0);                // 36864
    unsigned short* qb   = (unsigned short*)(ws + 36864);   // 4718592
    unsigned short* kb   = (unsigned short*)(ws + 4755456); // 1179648
    unsigned short* vb   = (unsigned short*)(ws + 5935104); // 1179648

    prep_kernel<<<dim3((B_*M_)/32), dim3(256), 0, stream>>>(x, c2, w_q, b_q,
        w_ea1, bn_w, bn_b, bn_m, bn_v, w_ea2, b_ea2, kb, vb, ea);
    qk_kernel<<<dim3((B_*N_)/32), dim3(256), 0, stream>>>(x, w_q, b_q, qb);
    attn_kernel<<<dim3(B_*QB_), dim3(256), 0, stream>>>(qb, kb, vb, ea, x, gamma, out);
}

// Round 12
// 164.596 us; speedup vs baseline: 1.2539x; 1.2539x over previous
//
#include <hip/hip_runtime.h>
#include <stdint.h>

#define B_ 4
#define C_ 64
#define H_ 96
#define W_ 96
#define HP_ 48
#define WP_ 48
#define N_ (H_*W_)      // 9216
#define M_ (HP_*WP_)    // 2304
#define KD_ 64
#define OD_ 64
#define BN_EPS 1e-5f
#define LOG2E 1.4426950408889634f
#define SHIFT2 28.853900817779268f   // 20 * LOG2E
#define QT_ 48                        // q-tile: 768 blocks = exactly 3/CU (balanced)
#define QB_ (N_/QT_)                  // 192 q-tiles per batch

typedef __bf16 bf16_t;
typedef bf16_t bf16x8 __attribute__((ext_vector_type(8)));
typedef bf16_t bf16x4 __attribute__((ext_vector_type(4)));
typedef float f32x4 __attribute__((ext_vector_type(4)));
typedef short short4v __attribute__((ext_vector_type(4)));

static __device__ __forceinline__ unsigned short f2bf(float f) {
    unsigned int u = __builtin_bit_cast(unsigned int, f);
    u += 0x7fffu + ((u >> 16) & 1u);
    return (unsigned short)(u >> 16);
}

// Host-safe wrapper (builtin only exists in the device pass; R4/R6 verified
// this MFMA's C/D layout on HW: absmax 0.03125).
static __device__ __forceinline__ f32x4 mfma16_bf16(short4v a, short4v b, f32x4 c) {
#if __has_builtin(__builtin_amdgcn_mfma_f32_16x16x16bf16_1k)
    return __builtin_amdgcn_mfma_f32_16x16x16bf16_1k(a, b, c, 0, 0, 0);
#else
    return c;  // host pass only — never executed on device
#endif
}

// ---------------- Kernel 1: fused pool(x,c2) + key conv + edge attention ----------------
// ea output pre-scaled by LOG2E.
__global__ __launch_bounds__(256) void prep_kernel(
    const float* __restrict__ x, const float* __restrict__ c2,
    const float* __restrict__ wq, const float* __restrict__ bq,
    const float* __restrict__ w1, const float* __restrict__ bnw, const float* __restrict__ bnb,
    const float* __restrict__ bnm, const float* __restrict__ bnv,
    const float* __restrict__ w2, const float* __restrict__ b2,
    unsigned short* __restrict__ kb, unsigned short* __restrict__ vb, float* __restrict__ ea) {

    __shared__ float lw1[OD_*2*C_];
    __shared__ float lwq[KD_*C_];
    __shared__ float xs[C_*33];
    __shared__ float c2s[C_*33];
    __shared__ float red[8][32];

    int tid = threadIdx.x;
    int b = blockIdx.x / 72;
    int m0 = (blockIdx.x % 72) * 32;

    for (int i = tid; i < OD_*2*C_; i += 256) lw1[i] = w1[i];
    for (int i = tid; i < KD_*C_; i += 256) lwq[i] = wq[i];
    for (int j = tid; j < 2048; j += 256) {
        int c = j >> 5, p = j & 31;
        int m = m0 + p;
        int hp = m / WP_, wp = m % WP_;
        size_t base = ((size_t)(b*C_ + c)*H_ + 2*hp)*W_ + 2*wp;
        const float* px = x + base;
        float mx = fmaxf(fmaxf(px[0], px[1]), fmaxf(px[W_], px[W_+1]));
        xs[c*33 + p] = mx;
        vb[(size_t)(b*C_ + c)*M_ + m] = f2bf(mx);
        const float* pc = c2 + base;
        c2s[c*33 + p] = fmaxf(fmaxf(pc[0], pc[1]), fmaxf(pc[W_], pc[W_+1]));
    }
    __syncthreads();

    int ml = tid & 31, oz = tid >> 5;
    int m = m0 + ml;

    float h[8] = {0,0,0,0,0,0,0,0};
    for (int c = 0; c < C_; c += 4) {
        float x0 = xs[c*33+ml], x1 = xs[(c+1)*33+ml], x2 = xs[(c+2)*33+ml], x3 = xs[(c+3)*33+ml];
        #pragma unroll
        for (int oi = 0; oi < 8; oi++) {
            const float4 wv = *(const float4*)&lwq[(oz*8 + oi)*C_ + c];
            h[oi] = fmaf(wv.x, x0, fmaf(wv.y, x1, fmaf(wv.z, x2, fmaf(wv.w, x3, h[oi]))));
        }
    }
    unsigned short tmp[8];
    #pragma unroll
    for (int oi = 0; oi < 8; oi++) tmp[oi] = f2bf(h[oi] + bq[oz*8 + oi]);
    *(uint4*)&kb[((size_t)b*M_ + m)*KD_ + oz*8] = *(const uint4*)tmp;

    float g[8] = {0,0,0,0,0,0,0,0};
    for (int c = 0; c < 2*C_; c += 4) {
        const float* srcb = (c < C_) ? &c2s[c*33] : &xs[(c - C_)*33];
        float x0 = srcb[ml], x1 = srcb[33+ml], x2 = srcb[66+ml], x3 = srcb[99+ml];
        #pragma unroll
        for (int oi = 0; oi < 8; oi++) {
            const float4 wv = *(const float4*)&lw1[(oz*8 + oi)*(2*C_) + c];
            g[oi] = fmaf(wv.x, x0, fmaf(wv.y, x1, fmaf(wv.z, x2, fmaf(wv.w, x3, g[oi]))));
        }
    }
    float z = 0.f;
    #pragma unroll
    for (int oi = 0; oi < 8; oi++) {
        int o = oz*8 + oi;
        float sc = bnw[o] * rsqrtf(bnv[o] + BN_EPS);
        float t = (g[oi] - bnm[o]) * sc + bnb[o];
        z += w2[o] * fmaxf(t, 0.f);
    }
    red[oz][ml] = z;
    __syncthreads();
    if (oz == 0) {
        float s = b2[0];
        #pragma unroll
        for (int i = 0; i < 8; i++) s += red[i][ml];
        ea[(size_t)b*M_ + m] = LOG2E / (1.f + __builtin_amdgcn_exp2f(-s * LOG2E));
    }
}

// ---------------- Kernel 2: query conv at full res -> bf16 [b][n][64] ----------------
__global__ __launch_bounds__(256) void qk_kernel(const float* __restrict__ in, const float* __restrict__ wq,
    const float* __restrict__ bq, unsigned short* __restrict__ outb) {
    __shared__ float lw[KD_*C_];
    for (int i = threadIdx.x; i < KD_*C_; i += 256) lw[i] = wq[i];
    __syncthreads();
    int ml = threadIdx.x & 31, oz = threadIdx.x >> 5;
    int pg = blockIdx.x * 32 + ml;
    float h[8] = {0,0,0,0,0,0,0,0};
    const float* src = in + ((size_t)(pg / N_))*C_*N_ + (pg % N_);
    for (int c = 0; c < C_; c += 4) {
        float x0 = src[(size_t)c*N_], x1 = src[(size_t)(c+1)*N_];
        float x2 = src[(size_t)(c+2)*N_], x3 = src[(size_t)(c+3)*N_];
        #pragma unroll
        for (int oi = 0; oi < 8; oi++) {
            const float4 wv = *(const float4*)&lw[(oz*8 + oi)*C_ + c];
            h[oi] = fmaf(wv.x, x0, fmaf(wv.y, x1, fmaf(wv.z, x2, fmaf(wv.w, x3, h[oi]))));
        }
    }
    unsigned short tmp[8];
    #pragma unroll
    for (int oi = 0; oi < 8; oi++) tmp[oi] = f2bf(h[oi] + bq[oz*8 + oi]);
    *(uint4*)&outb[(size_t)pg*KD_ + oz*8] = *(const uint4*)tmp;
}

// ---------------- Kernel 3: flash attention (R9 structure + ones-MFMA l-sum) ----------------
// grid = 768 (exactly 3 blocks/CU), block = 256 (4 waves) = 48 q-rows of one batch.
// XCD swizzle: batch = (blk&7)>>1 -> each batch's ~1.8 MB working set lives in
// one 2-XCD L2 pair. Wave w owns m-substrip [mt*64+16w, +16) for ALL 48 q;
// K/V staged coalesced in LDS (dbuf, 1 barrier/tile) — frag reads MUST be
// LDS-served (R4/R11: direct-global frag gathers are 2x slower). P stays in
// registers (S^T D-layout == K=16 MFMA B-layout); softmax denominator via
// all-ones A-frag MFMA (R10/R11-verified, deletes VALU adds + epilogue shuffles).
__global__ __launch_bounds__(256, 3) void attn_kernel(
    const unsigned short* __restrict__ qb, const unsigned short* __restrict__ kb,
    const unsigned short* __restrict__ vb, const float* __restrict__ ea,
    const float* __restrict__ x, const float* __restrict__ gamma_p, float* __restrict__ out) {

    // k0:0(9216) v0:9216 k1:18432 v1:27648 -> 36864 B
    // epilogue overlay: o_red 2*48*68*4=26112 + l_red 768 -> 26880 B
    __shared__ __align__(16) char smem[36864];

    int tid = threadIdx.x;
    int wave = tid >> 6, lane = tid & 63, quad = lane >> 4, l16 = lane & 15;
    int blk = blockIdx.x;
    int b = (blk & 7) >> 1;                       // batch pinned to XCD pair
    int n_base = ((blk & 1) * (QB_/2) + (blk >> 3)) * QT_;

    // Q B-frags: B[col = q = qi*16+l16][k = quad*8+j]
    bf16x8 qf[3][2];
    #pragma unroll
    for (int qi = 0; qi < 3; qi++) {
        const unsigned short* qp = qb + ((size_t)b*N_ + n_base + qi*16 + l16)*KD_;
        qf[qi][0] = __builtin_bit_cast(bf16x8, *(const uint4*)(qp + quad*8));
        qf[qi][1] = __builtin_bit_cast(bf16x8, *(const uint4*)(qp + 32 + quad*8));
    }

    f32x4 o2[3][4];   // O^T partial: [qi][ct]; D: row=c=ct*16+quad*4+r, col=q=qi*16+l16
    f32x4 lacc[3];    // denominator partials via ones-MFMA (all D rows identical)
    #pragma unroll
    for (int qi = 0; qi < 3; qi++) {
        lacc[qi] = (f32x4){0.f,0.f,0.f,0.f};
        #pragma unroll
        for (int ct = 0; ct < 4; ct++) o2[qi][ct] = (f32x4){0.f,0.f,0.f,0.f};
    }
    const short one_bf = (short)0x3F80;  // bf16 1.0
    short4v ones = (short4v){one_bf, one_bf, one_bf, one_bf};

    const unsigned short* kbB = kb + (size_t)b*M_*KD_;
    const unsigned short* vbB = vb + (size_t)b*C_*M_;
    const float* eaB = ea + (size_t)b*M_;

    int r0 = tid >> 3, g8 = (tid & 7) << 3;
    uint4 kA, kB, vA, vB;

    // prologue: stage tile 0 into buffer 0
    {
        kA = *(const uint4*)(kbB + (size_t)r0*KD_ + g8);
        kB = *(const uint4*)(kbB + (size_t)(r0+32)*KD_ + g8);
        vA = *(const uint4*)(vbB + (size_t)r0*M_ + g8);
        vB = *(const uint4*)(vbB + (size_t)(r0+32)*M_ + g8);
        unsigned short* k0 = (unsigned short*)smem;
        unsigned short* v0 = (unsigned short*)(smem + 9216);
        *(uint4*)(k0 + r0*72 + g8) = kA;
        *(uint4*)(k0 + (r0+32)*72 + g8) = kB;
        *(uint4*)(v0 + r0*72 + g8) = vA;
        *(uint4*)(v0 + (r0+32)*72 + g8) = vB;
    }
    __syncthreads();

    for (int mt = 0; mt < M_/64; mt++) {
        int cur = mt & 1;
        if (mt < M_/64 - 1) {
            int mb = (mt+1) * 64;
            kA = *(const uint4*)(kbB + (size_t)(mb + r0)*KD_ + g8);
            kB = *(const uint4*)(kbB + (size_t)(mb + r0 + 32)*KD_ + g8);
            vA = *(const uint4*)(vbB + (size_t)r0*M_ + mb + g8);
            vB = *(const uint4*)(vbB + (size_t)(r0+32)*M_ + mb + g8);
        }
        unsigned short* kc = (unsigned short*)(smem + cur*18432);
        unsigned short* vc = (unsigned short*)(smem + cur*18432 + 9216);

        // ea broadcast for this wave's strip (L1-served, 4 distinct addrs/wave)
        f32x4 e4 = *(const f32x4*)(eaB + mt*64 + wave*16 + quad*4);

        // K A-frag + V A-frags up front: overlap LDS latency with the MFMAs
        bf16x8 kf0 = __builtin_bit_cast(bf16x8, *(const uint4*)(kc + (wave*16 + l16)*72 + quad*8));
        bf16x8 kf1 = __builtin_bit_cast(bf16x8, *(const uint4*)(kc + (wave*16 + l16)*72 + 32 + quad*8));
        short4v va[4];
        #pragma unroll
        for (int ct = 0; ct < 4; ct++)
            va[ct] = *(const short4v*)(vc + (ct*16 + l16)*72 + wave*16 + quad*4);

        // S^T strip: D[m_local = quad*4+r][q = qi*16+l16]
        f32x4 st[3];
        #pragma unroll
        for (int qi = 0; qi < 3; qi++) {
            f32x4 z = (f32x4){0.f,0.f,0.f,0.f};
            z = __builtin_amdgcn_mfma_f32_16x16x32_bf16(kf0, qf[qi][0], z, 0, 0, 0);
            z = __builtin_amdgcn_mfma_f32_16x16x32_bf16(kf1, qf[qi][1], z, 0, 0, 0);
            st[qi] = z;
        }

        // fixed-shift softmax numerators; packed cvt (v_cvt_pk_bf16_f32)
        short4v pk[3];
        #pragma unroll
        for (int qi = 0; qi < 3; qi++) {
            f32x4 p;
            p[0] = __builtin_amdgcn_exp2f(fmaf(st[qi][0], e4[0], -SHIFT2));
            p[1] = __builtin_amdgcn_exp2f(fmaf(st[qi][1], e4[1], -SHIFT2));
            p[2] = __builtin_amdgcn_exp2f(fmaf(st[qi][2], e4[2], -SHIFT2));
            p[3] = __builtin_amdgcn_exp2f(fmaf(st[qi][3], e4[3], -SHIFT2));
            pk[qi] = __builtin_bit_cast(short4v, __builtin_convertvector(p, bf16x4));
        }

        // PV (A = V^T strip frag, B = P) + denominator via ones-A MFMA
        #pragma unroll
        for (int ct = 0; ct < 4; ct++)
            #pragma unroll
            for (int qi = 0; qi < 3; qi++)
                o2[qi][ct] = mfma16_bf16(va[ct], pk[qi], o2[qi][ct]);
        #pragma unroll
        for (int qi = 0; qi < 3; qi++)
            lacc[qi] = mfma16_bf16(ones, pk[qi], lacc[qi]);

        if (mt < M_/64 - 1) {
            int nxt = 1 - cur;
            unsigned short* kd = (unsigned short*)(smem + nxt*18432);
            unsigned short* vd = (unsigned short*)(smem + nxt*18432 + 9216);
            *(uint4*)(kd + r0*72 + g8) = kA;
            *(uint4*)(kd + (r0+32)*72 + g8) = kB;
            *(uint4*)(vd + r0*72 + g8) = vA;
            *(uint4*)(vd + (r0+32)*72 + g8) = vB;
        }
        __syncthreads();
    }

    // ---- epilogue: cross-wave reduction of O^T partials and denominators ----
    float* o_red0 = (float*)smem;            // [48 q][68 c]
    float* o_red1 = o_red0 + 48*68;
    float* l_red  = o_red1 + 48*68;          // [4][48]

    if (lane < 16) {
        #pragma unroll
        for (int qi = 0; qi < 3; qi++) l_red[wave*48 + qi*16 + l16] = lacc[qi][0];
    }
    if (wave < 2) {
        float* od = (wave == 0) ? o_red0 : o_red1;
        #pragma unroll
        for (int qi = 0; qi < 3; qi++)
            #pragma unroll
            for (int ct = 0; ct < 4; ct++)
                *(f32x4*)&od[(qi*16 + l16)*68 + ct*16 + quad*4] = o2[qi][ct];
    }
    __syncthreads();
    if (wave >= 2) {
        float* od = (wave == 2) ? o_red0 : o_red1;
        #pragma unroll
        for (int qi = 0; qi < 3; qi++)
            #pragma unroll
            for (int ct = 0; ct < 4; ct++) {
                f32x4* p = (f32x4*)&od[(qi*16 + l16)*68 + ct*16 + quad*4];
                *p += o2[qi][ct];
            }
    }
    __syncthreads();
    if (tid < 48) {
        float s = (l_red[tid] + l_red[48 + tid]) + (l_red[96 + tid] + l_red[144 + tid]);
        l_red[tid] = 1.f / s;
    }
    __syncthreads();

    float gmm = gamma_p[0];
    int c = tid >> 2, q4 = tid & 3;
    const float* xrow = x + ((size_t)b*C_ + c)*N_ + n_base;
    float* orow = out + ((size_t)b*C_ + c)*N_ + n_base;
    #pragma unroll
    for (int i = 0; i < 3; i++) {
        int q0 = q4*4 + i*16;
        float4 xv = *(const float4*)(xrow + q0);
        float4 ov;
        float v0 = (o_red0[(q0+0)*68 + c] + o_red1[(q0+0)*68 + c]) * l_red[q0+0];
        float v1 = (o_red0[(q0+1)*68 + c] + o_red1[(q0+1)*68 + c]) * l_red[q0+1];
        float v2 = (o_red0[(q0+2)*68 + c] + o_red1[(q0+2)*68 + c]) * l_red[q0+2];
        float v3 = (o_red0[(q0+3)*68 + c] + o_red1[(q0+3)*68 + c]) * l_red[q0+3];
        ov.x = fmaf(gmm, v0, xv.x);
        ov.y = fmaf(gmm, v1, xv.y);
        ov.z = fmaf(gmm, v2, xv.z);
        ov.w = fmaf(gmm, v3, xv.w);
        *(float4*)(orow + q0) = ov;
    }
}

extern "C" void kernel_launch(void* const* d_in, const int* in_sizes, int n_in,
                              void* d_out, int out_size, void* d_ws, size_t ws_size,
                              hipStream_t stream) {
    const float* c2    = (const float*)d_in[0];
    const float* x     = (const float*)d_in[1];
    const float* w_ea1 = (const float*)d_in[2];
    const float* bn_w  = (const float*)d_in[3];
    const float* bn_b  = (const float*)d_in[4];
    const float* bn_m  = (const float*)d_in[5];
    const float* bn_v  = (const float*)d_in[6];
    const float* w_ea2 = (const float*)d_in[7];
    const float* b_ea2 = (const float*)d_in[8];
    const float* w_q   = (const float*)d_in[9];
    const float* b_q   = (const float*)d_in[10];
    const float* gamma = (const float*)d_in[11];
    float* out = (float*)d_out;

    char* ws = (char*)d_ws;
    float* ea            = (float*)(ws + 0);                // 36864
    unsigned short* qb   = (unsigned short*)(ws + 36864);   // 4718592
    unsigned short* kb   = (unsigned short*)(ws + 4755456); // 1179648
    unsigned short* vb   = (unsigned short*)(ws + 5935104); // 1179648

    prep_kernel<<<dim3((B_*M_)/32), dim3(256), 0, stream>>>(x, c2, w_q, b_q,
        w_ea1, bn_w, bn_b, bn_m, bn_v, w_ea2, b_ea2, kb, vb, ea);
    qk_kernel<<<dim3((B_*N_)/32), dim3(256), 0, stream>>>(x, w_q, b_q, qb);
    attn_kernel<<<dim3(B_*QB_), dim3(256), 0, stream>>>(qb, kb, vb, ea, x, gamma, out);
}